// Round 2
// baseline (1861.882 us; speedup 1.0000x reference)
//
#include <hip/hip_runtime.h>

#define N_NODES 100000
#define IN_DIM 64
#define EMB 128
#define N_EDGES 1600000
#define BN_EPS 1e-5f

// ---------------- Kernel A: scatter-add  agg[dst] += x[src] * w ----------------
// One thread per (edge, 4-feature chunk): 16 threads/edge, float4 gather, 4 atomics.
__global__ __launch_bounds__(256) void scatter_kernel(
    const float* __restrict__ x,
    const int* __restrict__ ei,   // [2, E] int32 (harness passes integers as int32)
    const float* __restrict__ ew,
    float* __restrict__ agg)
{
    long long gid = (long long)blockIdx.x * blockDim.x + threadIdx.x;
    if (gid >= (long long)N_EDGES * 16) return;
    int e = (int)(gid >> 4);
    int q = (int)(gid & 15);
    int src = ei[e];
    int dst = ei[N_EDGES + e];
    float w = ew[e];
    float4 v = ((const float4*)(x + (long long)src * IN_DIM))[q];
    float* p = agg + (long long)dst * IN_DIM + q * 4;
    atomicAdd(p + 0, v.x * w);
    atomicAdd(p + 1, v.y * w);
    atomicAdd(p + 2, v.z * w);
    atomicAdd(p + 3, v.w * w);
}

// ---------------- Kernel B: h = (agg + x) @ W1 + b1 ----------------
#define B_ROWS 40
__global__ __launch_bounds__(128) void mlp1_kernel(
    const float* __restrict__ agg,
    const float* __restrict__ x,
    const float* __restrict__ W1,   // [64,128] row-major
    const float* __restrict__ b1,
    float* __restrict__ h)          // [N,128]
{
    __shared__ float w1s[IN_DIM][EMB];   // 32 KB
    __shared__ float rowbuf[IN_DIM];
    int tid = threadIdx.x;  // 0..127
    for (int i = tid; i < IN_DIM * EMB; i += 128)
        w1s[i >> 7][i & 127] = W1[i];
    float bj = b1[tid];
    int row0 = blockIdx.x * B_ROWS;
    for (int r = 0; r < B_ROWS; ++r) {
        int row = row0 + r;
        __syncthreads();   // protects rowbuf reuse + (r==0) W1 visibility
        if (tid < IN_DIM)
            rowbuf[tid] = agg[(long long)row * IN_DIM + tid] + x[(long long)row * IN_DIM + tid];
        __syncthreads();
        float acc = bj;
        #pragma unroll
        for (int k = 0; k < IN_DIM; ++k)
            acc += rowbuf[k] * w1s[k][tid];
        h[(long long)row * EMB + tid] = acc;
    }
}

// ---------------- Kernel C: per-column sum & sumsq over rows ----------------
__global__ __launch_bounds__(256) void stats_kernel(
    const float* __restrict__ h,
    float* __restrict__ gsum, float* __restrict__ gsum2)
{
    int tid = threadIdx.x;       // 256
    int c = tid & 127;
    int half = tid >> 7;         // 0/1
    long long row = (long long)blockIdx.x * 2 + half;
    long long stride = (long long)gridDim.x * 2;
    float s = 0.f, s2 = 0.f;
    for (; row < N_NODES; row += stride) {
        float v = h[row * EMB + c];
        s += v; s2 += v * v;
    }
    __shared__ float ls[2][128], ls2[2][128];
    ls[half][c] = s; ls2[half][c] = s2;
    __syncthreads();
    if (half == 0) {
        atomicAdd(&gsum[c],  ls[0][c] + ls[1][c]);
        atomicAdd(&gsum2[c], ls2[0][c] + ls2[1][c]);
    }
}

// ---------------- Kernel E: out = relu(BN(h)) @ W2 + b2, in-place on h ----------------
#define E_ROWS 40
__global__ __launch_bounds__(128) void mlp2_kernel(
    float* __restrict__ hio,        // [N,128] in: h, out: final
    const float* __restrict__ gsum, const float* __restrict__ gsum2,
    const float* __restrict__ gamma, const float* __restrict__ beta,
    const float* __restrict__ W2,   // [128,128] row-major
    const float* __restrict__ b2)
{
    __shared__ float w2s[EMB][EMB];   // 64 KB
    __shared__ float nbuf[EMB];
    int tid = threadIdx.x;  // 0..127
    for (int i = tid; i < EMB * EMB; i += 128)
        w2s[i >> 7][i & 127] = W2[i];
    const float invN = 1.0f / (float)N_NODES;
    float mean = gsum[tid] * invN;
    float var  = gsum2[tid] * invN - mean * mean;
    float inv  = rsqrtf(var + BN_EPS);
    float a    = gamma[tid] * inv;
    float bb   = beta[tid] - mean * a;
    float bj   = b2[tid];
    int row0 = blockIdx.x * E_ROWS;
    for (int r = 0; r < E_ROWS; ++r) {
        long long row = row0 + r;
        __syncthreads();   // protects nbuf reuse + (r==0) W2 visibility
        float hv = hio[row * EMB + tid];
        nbuf[tid] = fmaxf(hv * a + bb, 0.f);
        __syncthreads();
        float acc = bj;
        #pragma unroll 8
        for (int k = 0; k < EMB; ++k)
            acc += nbuf[k] * w2s[k][tid];
        hio[row * EMB + tid] = acc;
    }
}

extern "C" void kernel_launch(void* const* d_in, const int* in_sizes, int n_in,
                              void* d_out, int out_size, void* d_ws, size_t ws_size,
                              hipStream_t stream)
{
    const float* x     = (const float*)d_in[0];
    const int*   ei    = (const int*)d_in[1];   // int32!
    // d_in[2] = edge_attr (unused)
    const float* ew    = (const float*)d_in[3];
    const float* W1    = (const float*)d_in[4];
    const float* b1    = (const float*)d_in[5];
    const float* gamma = (const float*)d_in[6];
    const float* beta  = (const float*)d_in[7];
    const float* W2    = (const float*)d_in[8];
    const float* b2    = (const float*)d_in[9];

    float* agg   = (float*)d_ws;                       // 25,600,000 B
    float* gsum  = (float*)((char*)d_ws + 25600000);   // 512 B
    float* gsum2 = (float*)((char*)d_ws + 25600512);   // 512 B
    float* h     = (float*)d_out;                      // staged h, then final out

    // zero agg + stats accumulators (every launch; ws not preserved between replays)
    hipMemsetAsync(d_ws, 0, 25601024, stream);

    // A: scatter
    {
        long long total = (long long)N_EDGES * 16;
        int blocks = (int)((total + 255) / 256);
        scatter_kernel<<<blocks, 256, 0, stream>>>(x, ei, ew, agg);
    }
    // B: first linear (+ self term)
    mlp1_kernel<<<N_NODES / B_ROWS, 128, 0, stream>>>(agg, x, W1, b1, h);
    // C: BN stats
    stats_kernel<<<1024, 256, 0, stream>>>(h, gsum, gsum2);
    // E: BN + ReLU + second linear (in-place on d_out)
    mlp2_kernel<<<N_NODES / E_ROWS, 128, 0, stream>>>(h, gsum, gsum2, gamma, beta, W2, b2);
}

// Round 3
// 835.415 us; speedup vs baseline: 2.2287x; 2.2287x over previous
//
#include <hip/hip_runtime.h>

#define N_NODES 100000
#define IN_DIM 64
#define EMB 128
#define N_EDGES 1600000
#define BN_EPS 1e-5f

// ---- workspace layout (bytes) ----
// 0        : rowstart  (N_NODES+1 ints)  400004  -> pad 400128
// 400128   : cursor    (N_NODES ints)    400000  -> pad 800256
// 800256   : gsum      (128 f)           512
// 800768   : gsum2     (128 f)           512     -> 801280
// 801280   : pairs     (N_EDGES float2)  12.8 MB -> ~13.6 MB total
#define WS_ROWSTART 0
#define WS_CURSOR   400128
#define WS_GSUM     800256
#define WS_GSUM2    800768
#define WS_PAIRS    801280
#define WS_ZERO_BYTES 801280

// ---------------- 1) histogram of dst ----------------
__global__ __launch_bounds__(256) void hist_kernel(
    const int* __restrict__ ei, int* __restrict__ rowstart)
{
    int e = blockIdx.x * 256 + threadIdx.x;
    if (e < N_EDGES) atomicAdd(&rowstart[1 + ei[N_EDGES + e]], 1);
}

// ---------------- 2) inclusive scan -> rowstart[i]=start(i), cursor copy ----------------
__global__ __launch_bounds__(1024) void scan_kernel(
    int* __restrict__ rowstart, int* __restrict__ cursor)
{
    __shared__ int partial[1024];
    const int t = threadIdx.x;
    const int chunk = 98;                       // 1024*98 >= 100001
    int lo = t * chunk;
    int hi = min(lo + chunk, N_NODES + 1);
    int s = 0;
    for (int i = lo; i < hi; ++i) s += rowstart[i];
    partial[t] = s;
    __syncthreads();
    for (int off = 1; off < 1024; off <<= 1) {
        int v = (t >= off) ? partial[t - off] : 0;
        __syncthreads();
        partial[t] += v;
        __syncthreads();
    }
    int run = (t > 0) ? partial[t - 1] : 0;
    for (int i = lo; i < hi; ++i) {
        run += rowstart[i];
        rowstart[i] = run;                      // inclusive: = start offset of node i
        if (i < N_NODES) cursor[i] = run;
    }
}

// ---------------- 3) fill (src, w) pairs per dst bucket ----------------
__global__ __launch_bounds__(256) void fill_kernel(
    const int* __restrict__ ei, const float* __restrict__ ew,
    int* __restrict__ cursor, float2* __restrict__ pairs)
{
    int e = blockIdx.x * 256 + threadIdx.x;
    if (e >= N_EDGES) return;
    int src = ei[e];
    int dst = ei[N_EDGES + e];
    int pos = atomicAdd(&cursor[dst], 1);
    pairs[pos] = make_float2(__int_as_float(src), ew[e]);
}

// ---------------- 4) fused gather + (agg+x)@W1+b1 + BN partial stats ----------------
#define B1_NPW 25   // nodes per wave
__global__ __launch_bounds__(256) void mlp1_kernel(
    const float* __restrict__ x,
    const int* __restrict__ rowstart,
    const float2* __restrict__ pairs,
    const float* __restrict__ W1,   // [64,128] row-major
    const float* __restrict__ b1,
    float* __restrict__ h,          // [N,128]
    float* __restrict__ gsum, float* __restrict__ gsum2)
{
    __shared__ float w1s[IN_DIM][EMB];     // 32 KB
    __shared__ float rowbuf[4][IN_DIM];    // per-wave row (no cross-wave sharing)
    __shared__ float red[4][2][EMB];       // per-wave col partials

    const int tid  = threadIdx.x;
    const int lane = tid & 63;
    const int wid  = tid >> 6;
    const int lane64 = lane + 64;

    for (int i = tid; i < IN_DIM * EMB; i += 256)
        w1s[i >> 7][i & 127] = W1[i];
    const float bl0 = b1[lane], bl1 = b1[lane64];
    __syncthreads();   // w1s ready

    float s0 = 0.f, s20 = 0.f, s1 = 0.f, s21 = 0.f;
    const int node0 = (blockIdx.x * 4 + wid) * B1_NPW;

    for (int r = 0; r < B1_NPW; ++r) {
        const int n  = node0 + r;
        const int jb = rowstart[n];
        const int je = rowstart[n + 1];

        // gather: lane = feature
        float acc = x[(size_t)n * IN_DIM + lane];     // self term (1+eps)=1
        for (int j0 = jb; j0 < je; j0 += 64) {
            const int cnt = min(64, je - j0);
            float2 p = (lane < cnt) ? pairs[j0 + lane] : make_float2(0.f, 0.f);
            int   psrc = __float_as_int(p.x);
            float pw   = p.y;
            #pragma unroll 4
            for (int t = 0; t < cnt; ++t) {
                int   src = __shfl(psrc, t);
                float w   = __shfl(pw, t);
                acc += w * x[(size_t)src * IN_DIM + lane];
            }
        }
        // wave-private LDS row (same-wave write->read; compiler inserts lgkmcnt)
        rowbuf[wid][lane] = acc;

        // GEMV: lane computes cols lane, lane+64
        float a0 = bl0, a1 = bl1;
        const float4* rb4 = (const float4*)rowbuf[wid];
        #pragma unroll
        for (int kg = 0; kg < 16; ++kg) {
            float4 rv = rb4[kg];
            int k = kg * 4;
            a0 += rv.x * w1s[k][lane]   + rv.y * w1s[k+1][lane]
                + rv.z * w1s[k+2][lane] + rv.w * w1s[k+3][lane];
            a1 += rv.x * w1s[k][lane64]   + rv.y * w1s[k+1][lane64]
                + rv.z * w1s[k+2][lane64] + rv.w * w1s[k+3][lane64];
        }
        h[(size_t)n * EMB + lane]   = a0;
        h[(size_t)n * EMB + lane64] = a1;
        s0 += a0; s20 += a0 * a0;
        s1 += a1; s21 += a1 * a1;
    }

    // block-reduce BN partials, one atomic per col pair per block
    red[wid][0][lane] = s0;  red[wid][0][lane64] = s1;
    red[wid][1][lane] = s20; red[wid][1][lane64] = s21;
    __syncthreads();
    if (tid < EMB) {
        float t0 = red[0][0][tid] + red[1][0][tid] + red[2][0][tid] + red[3][0][tid];
        float t1 = red[0][1][tid] + red[1][1][tid] + red[2][1][tid] + red[3][1][tid];
        atomicAdd(&gsum[tid],  t0);
        atomicAdd(&gsum2[tid], t1);
    }
}

// ---------------- 5) out = relu(BN(h)) @ W2 + b2 (in-place on h) ----------------
#define E_ROWS 40   // rows per block
__global__ __launch_bounds__(256) void mlp2_kernel(
    float* __restrict__ hio,
    const float* __restrict__ gsum, const float* __restrict__ gsum2,
    const float* __restrict__ gamma, const float* __restrict__ beta,
    const float* __restrict__ W2,   // [128,128] row-major
    const float* __restrict__ b2)
{
    __shared__ float w2t[EMB][132];   // transposed + padded: w2t[j][k] = W2[k][j]; 67.6 KB
    __shared__ float nbuf[8][EMB];    // 8 rows of relu(BN(h))

    const int tid = threadIdx.x;
    const int col = tid & 127;
    const int rh  = tid >> 7;         // 0/1: row half

    for (int i = tid; i < EMB * EMB; i += 256) {
        int k = i >> 7, j = i & 127;
        w2t[j][k] = W2[i];
    }
    const float invN = 1.0f / (float)N_NODES;
    float mean = gsum[col] * invN;
    float var  = gsum2[col] * invN - mean * mean;
    float inv  = rsqrtf(var + BN_EPS);
    float a    = gamma[col] * inv;
    float bb   = beta[col] - mean * a;
    float bj   = b2[col];

    const int row0 = blockIdx.x * E_ROWS;
    for (int it = 0; it < E_ROWS / 8; ++it) {
        const int rbase = row0 + it * 8;
        __syncthreads();   // protect nbuf reuse
        #pragma unroll
        for (int rr = 0; rr < 4; ++rr) {
            int lr = rh * 4 + rr;
            float hv = hio[(size_t)(rbase + lr) * EMB + col];
            nbuf[lr][col] = fmaxf(hv * a + bb, 0.f);
        }
        __syncthreads();
        float4 acc = make_float4(bj, bj, bj, bj);   // 4 rows of this half
        const float4* wt4 = (const float4*)&w2t[col][0];
        const float4* n0 = (const float4*)&nbuf[rh * 4 + 0][0];
        const float4* n1 = (const float4*)&nbuf[rh * 4 + 1][0];
        const float4* n2 = (const float4*)&nbuf[rh * 4 + 2][0];
        const float4* n3 = (const float4*)&nbuf[rh * 4 + 3][0];
        #pragma unroll 8
        for (int kg = 0; kg < 32; ++kg) {
            float4 wv = wt4[kg];
            float4 v0 = n0[kg], v1 = n1[kg], v2 = n2[kg], v3 = n3[kg];
            acc.x += wv.x*v0.x + wv.y*v0.y + wv.z*v0.z + wv.w*v0.w;
            acc.y += wv.x*v1.x + wv.y*v1.y + wv.z*v1.z + wv.w*v1.w;
            acc.z += wv.x*v2.x + wv.y*v2.y + wv.z*v2.z + wv.w*v2.w;
            acc.w += wv.x*v3.x + wv.y*v3.y + wv.z*v3.z + wv.w*v3.w;
        }
        hio[(size_t)(rbase + rh*4 + 0) * EMB + col] = acc.x;
        hio[(size_t)(rbase + rh*4 + 1) * EMB + col] = acc.y;
        hio[(size_t)(rbase + rh*4 + 2) * EMB + col] = acc.z;
        hio[(size_t)(rbase + rh*4 + 3) * EMB + col] = acc.w;
    }
}

extern "C" void kernel_launch(void* const* d_in, const int* in_sizes, int n_in,
                              void* d_out, int out_size, void* d_ws, size_t ws_size,
                              hipStream_t stream)
{
    const float* x     = (const float*)d_in[0];
    const int*   ei    = (const int*)d_in[1];   // int32 [2,E]
    const float* ew    = (const float*)d_in[3];
    const float* W1    = (const float*)d_in[4];
    const float* b1    = (const float*)d_in[5];
    const float* gamma = (const float*)d_in[6];
    const float* beta  = (const float*)d_in[7];
    const float* W2    = (const float*)d_in[8];
    const float* b2    = (const float*)d_in[9];

    char* ws = (char*)d_ws;
    int*    rowstart = (int*)(ws + WS_ROWSTART);
    int*    cursor   = (int*)(ws + WS_CURSOR);
    float*  gsum     = (float*)(ws + WS_GSUM);
    float*  gsum2    = (float*)(ws + WS_GSUM2);
    float2* pairs    = (float2*)(ws + WS_PAIRS);
    float*  h        = (float*)d_out;

    hipMemsetAsync(d_ws, 0, WS_ZERO_BYTES, stream);

    hist_kernel<<<(N_EDGES + 255) / 256, 256, 0, stream>>>(ei, rowstart);
    scan_kernel<<<1, 1024, 0, stream>>>(rowstart, cursor);
    fill_kernel<<<(N_EDGES + 255) / 256, 256, 0, stream>>>(ei, ew, cursor, pairs);
    mlp1_kernel<<<N_NODES / (4 * B1_NPW), 256, 0, stream>>>(x, rowstart, pairs, W1, b1, h, gsum, gsum2);
    mlp2_kernel<<<N_NODES / E_ROWS, 256, 0, stream>>>(h, gsum, gsum2, gamma, beta, W2, b2);
}

// Round 4
// 674.374 us; speedup vs baseline: 2.7609x; 1.2388x over previous
//
#include <hip/hip_runtime.h>

#define N_NODES 100000
#define IN_DIM 64
#define EMB 128
#define N_EDGES 1600000
#define BN_EPS 1e-5f

// ---- workspace layout (bytes) ----
// 0       : rowstart (N_NODES+1 ints) 400004 -> pad 400128   [zeroed]
// 400128  : gsum   (128 f) 512                               [zeroed]
// 400640  : gsum2  (128 f) 512  -> 401152                    [zeroed]
// 401152  : cursor (N_NODES ints) 400000 -> pad 801280       [written by scan]
// 801280  : pairs  (N_EDGES float2) 12.8 MB
#define WS_ROWSTART 0
#define WS_GSUM     400128
#define WS_GSUM2    400640
#define WS_CURSOR   401152
#define WS_PAIRS    801280
#define WS_ZERO_BYTES 401152

// ---------------- 1) histogram of dst ----------------
__global__ __launch_bounds__(256) void hist_kernel(
    const int* __restrict__ ei, int* __restrict__ rowstart)
{
    int e = blockIdx.x * 256 + threadIdx.x;
    if (e < N_EDGES) atomicAdd(&rowstart[1 + ei[N_EDGES + e]], 1);
}

// ---------------- 2) inclusive scan -> rowstart[i]=start(i), cursor copy ----------------
__global__ __launch_bounds__(1024) void scan_kernel(
    int* __restrict__ rowstart, int* __restrict__ cursor)
{
    __shared__ int partial[1024];
    const int t = threadIdx.x;
    const int chunk = 98;                       // 1024*98 >= 100001
    int lo = t * chunk;
    int hi = min(lo + chunk, N_NODES + 1);
    int s = 0;
    for (int i = lo; i < hi; ++i) s += rowstart[i];
    partial[t] = s;
    __syncthreads();
    for (int off = 1; off < 1024; off <<= 1) {
        int v = (t >= off) ? partial[t - off] : 0;
        __syncthreads();
        partial[t] += v;
        __syncthreads();
    }
    int run = (t > 0) ? partial[t - 1] : 0;
    for (int i = lo; i < hi; ++i) {
        run += rowstart[i];
        rowstart[i] = run;                      // = start offset of node i
        if (i < N_NODES) cursor[i] = run;
    }
}

// ---------------- 3) fill (src, w) pairs per dst bucket ----------------
__global__ __launch_bounds__(256) void fill_kernel(
    const int* __restrict__ ei, const float* __restrict__ ew,
    int* __restrict__ cursor, float2* __restrict__ pairs)
{
    int e = blockIdx.x * 256 + threadIdx.x;
    if (e >= N_EDGES) return;
    int src = ei[e];
    int dst = ei[N_EDGES + e];
    int pos = atomicAdd(&cursor[dst], 1);
    pairs[pos] = make_float2(__int_as_float(src), ew[e]);
}

// ---------------- 4) fused gather + (agg+x)@W1+b1 + BN partial stats ----------------
#define B1_NPW 5   // nodes per wave -> grid = 100000/(4*5) = 5000 blocks
__global__ __launch_bounds__(256) void mlp1_kernel(
    const float* __restrict__ x,
    const int* __restrict__ rowstart,
    const float2* __restrict__ pairs,
    const float* __restrict__ W1,   // [64,128] row-major
    const float* __restrict__ b1,
    float* __restrict__ h,          // [N,128]
    float* __restrict__ gsum, float* __restrict__ gsum2)
{
    __shared__ float w1s[IN_DIM][EMB];     // 32 KB
    __shared__ float rowbuf[4][IN_DIM];    // per-wave row
    __shared__ float red[4][2][EMB];       // per-wave col partials

    const int tid  = threadIdx.x;
    const int lane = tid & 63;
    const int wid  = tid >> 6;
    const int lane64 = lane + 64;

    for (int i = tid; i < IN_DIM * EMB; i += 256)
        w1s[i >> 7][i & 127] = W1[i];
    const float bl0 = b1[lane], bl1 = b1[lane64];
    __syncthreads();   // w1s ready

    float s0 = 0.f, s20 = 0.f, s1 = 0.f, s21 = 0.f;
    const int node0 = (blockIdx.x * 4 + wid) * B1_NPW;

    for (int r = 0; r < B1_NPW; ++r) {
        const int n  = node0 + r;
        const int jb = rowstart[n];
        const int je = rowstart[n + 1];

        // gather: lane = feature; edge chunks of 16, compile-time unrolled,
        // zero-weight padding for the tail (w=0 * x[row 0] is harmless).
        float accA = x[(size_t)n * IN_DIM + lane];   // self term, (1+eps)=1
        float accB = 0.f;
        for (int j0 = jb; j0 < je; j0 += 64) {
            const int cnt = min(64, je - j0);
            float2 p = (lane < cnt) ? pairs[j0 + lane] : make_float2(0.f, 0.f);
            int   psrc = __float_as_int(p.x);
            float pw   = p.y;
            const int nch = (cnt + 15) >> 4;
            for (int c = 0; c < nch; ++c) {
                const int base = c * 16;
                #pragma unroll
                for (int t = 0; t < 16; t += 2) {
                    int   sA = __shfl(psrc, base + t);
                    float wA = __shfl(pw,   base + t);
                    int   sB = __shfl(psrc, base + t + 1);
                    float wB = __shfl(pw,   base + t + 1);
                    accA += wA * x[(size_t)sA * IN_DIM + lane];
                    accB += wB * x[(size_t)sB * IN_DIM + lane];
                }
            }
        }
        rowbuf[wid][lane] = accA + accB;

        // GEMV: lane computes cols lane, lane+64
        float a0 = bl0, a1 = bl1;
        const float4* rb4 = (const float4*)rowbuf[wid];
        #pragma unroll
        for (int kg = 0; kg < 16; ++kg) {
            float4 rv = rb4[kg];
            int k = kg * 4;
            a0 += rv.x * w1s[k][lane]   + rv.y * w1s[k+1][lane]
                + rv.z * w1s[k+2][lane] + rv.w * w1s[k+3][lane];
            a1 += rv.x * w1s[k][lane64]   + rv.y * w1s[k+1][lane64]
                + rv.z * w1s[k+2][lane64] + rv.w * w1s[k+3][lane64];
        }
        h[(size_t)n * EMB + lane]   = a0;
        h[(size_t)n * EMB + lane64] = a1;
        s0 += a0; s20 += a0 * a0;
        s1 += a1; s21 += a1 * a1;
    }

    // block-reduce BN partials, one atomic per col per block
    red[wid][0][lane] = s0;  red[wid][0][lane64] = s1;
    red[wid][1][lane] = s20; red[wid][1][lane64] = s21;
    __syncthreads();
    if (tid < EMB) {
        float t0 = red[0][0][tid] + red[1][0][tid] + red[2][0][tid] + red[3][0][tid];
        float t1 = red[0][1][tid] + red[1][1][tid] + red[2][1][tid] + red[3][1][tid];
        atomicAdd(&gsum[tid],  t0);
        atomicAdd(&gsum2[tid], t1);
    }
}

// ---------------- 5) out = relu(BN(h)) @ W2 + b2 (in-place on h) ----------------
#define E_ROWS 40   // rows per block
__global__ __launch_bounds__(256) void mlp2_kernel(
    float* __restrict__ hio,
    const float* __restrict__ gsum, const float* __restrict__ gsum2,
    const float* __restrict__ gamma, const float* __restrict__ beta,
    const float* __restrict__ W2,   // [128,128] row-major
    const float* __restrict__ b2)
{
    __shared__ float w2t[EMB][132];   // transposed + padded: w2t[j][k] = W2[k][j]
    __shared__ float nbuf[8][EMB];    // 8 rows of relu(BN(h))

    const int tid = threadIdx.x;
    const int col = tid & 127;
    const int rh  = tid >> 7;         // 0/1: row half

    for (int i = tid; i < EMB * EMB; i += 256) {
        int k = i >> 7, j = i & 127;
        w2t[j][k] = W2[i];
    }
    const float invN = 1.0f / (float)N_NODES;
    float mean = gsum[col] * invN;
    float var  = gsum2[col] * invN - mean * mean;
    float inv  = rsqrtf(var + BN_EPS);
    float a    = gamma[col] * inv;
    float bb   = beta[col] - mean * a;
    float bj   = b2[col];

    const int row0 = blockIdx.x * E_ROWS;
    for (int it = 0; it < E_ROWS / 8; ++it) {
        const int rbase = row0 + it * 8;
        __syncthreads();   // protect nbuf reuse
        #pragma unroll
        for (int rr = 0; rr < 4; ++rr) {
            int lr = rh * 4 + rr;
            float hv = hio[(size_t)(rbase + lr) * EMB + col];
            nbuf[lr][col] = fmaxf(hv * a + bb, 0.f);
        }
        __syncthreads();
        float4 acc = make_float4(bj, bj, bj, bj);   // 4 rows of this half
        const float4* wt4 = (const float4*)&w2t[col][0];
        const float4* n0 = (const float4*)&nbuf[rh * 4 + 0][0];
        const float4* n1 = (const float4*)&nbuf[rh * 4 + 1][0];
        const float4* n2 = (const float4*)&nbuf[rh * 4 + 2][0];
        const float4* n3 = (const float4*)&nbuf[rh * 4 + 3][0];
        #pragma unroll 8
        for (int kg = 0; kg < 32; ++kg) {
            float4 wv = wt4[kg];
            float4 v0 = n0[kg], v1 = n1[kg], v2 = n2[kg], v3 = n3[kg];
            acc.x += wv.x*v0.x + wv.y*v0.y + wv.z*v0.z + wv.w*v0.w;
            acc.y += wv.x*v1.x + wv.y*v1.y + wv.z*v1.z + wv.w*v1.w;
            acc.z += wv.x*v2.x + wv.y*v2.y + wv.z*v2.z + wv.w*v2.w;
            acc.w += wv.x*v3.x + wv.y*v3.y + wv.z*v3.z + wv.w*v3.w;
        }
        hio[(size_t)(rbase + rh*4 + 0) * EMB + col] = acc.x;
        hio[(size_t)(rbase + rh*4 + 1) * EMB + col] = acc.y;
        hio[(size_t)(rbase + rh*4 + 2) * EMB + col] = acc.z;
        hio[(size_t)(rbase + rh*4 + 3) * EMB + col] = acc.w;
    }
}

extern "C" void kernel_launch(void* const* d_in, const int* in_sizes, int n_in,
                              void* d_out, int out_size, void* d_ws, size_t ws_size,
                              hipStream_t stream)
{
    const float* x     = (const float*)d_in[0];
    const int*   ei    = (const int*)d_in[1];   // int32 [2,E]
    const float* ew    = (const float*)d_in[3];
    const float* W1    = (const float*)d_in[4];
    const float* b1    = (const float*)d_in[5];
    const float* gamma = (const float*)d_in[6];
    const float* beta  = (const float*)d_in[7];
    const float* W2    = (const float*)d_in[8];
    const float* b2    = (const float*)d_in[9];

    char* ws = (char*)d_ws;
    int*    rowstart = (int*)(ws + WS_ROWSTART);
    int*    cursor   = (int*)(ws + WS_CURSOR);
    float*  gsum     = (float*)(ws + WS_GSUM);
    float*  gsum2    = (float*)(ws + WS_GSUM2);
    float2* pairs    = (float2*)(ws + WS_PAIRS);
    float*  h        = (float*)d_out;

    hipMemsetAsync(d_ws, 0, WS_ZERO_BYTES, stream);

    hist_kernel<<<(N_EDGES + 255) / 256, 256, 0, stream>>>(ei, rowstart);
    scan_kernel<<<1, 1024, 0, stream>>>(rowstart, cursor);
    fill_kernel<<<(N_EDGES + 255) / 256, 256, 0, stream>>>(ei, ew, cursor, pairs);
    mlp1_kernel<<<N_NODES / (4 * B1_NPW), 256, 0, stream>>>(x, rowstart, pairs, W1, b1, h, gsum, gsum2);
    mlp2_kernel<<<N_NODES / E_ROWS, 256, 0, stream>>>(h, gsum, gsum2, gamma, beta, W2, b2);
}

// Round 5
// 459.631 us; speedup vs baseline: 4.0508x; 1.4672x over previous
//
#include <hip/hip_runtime.h>

#define N_NODES 100000
#define IN_DIM 64
#define EMB 128
#define N_EDGES 1600000
#define BN_EPS 1e-5f

#define SCAN_ELEMS (N_NODES + 1)        // 100001
#define S1_EPB 1024                     // elements per block in scan phases
#define S1_BLOCKS ((SCAN_ELEMS + S1_EPB - 1) / S1_EPB)   // 98

// ---- workspace layout (bytes) ----
// 0       : rowstart (N_NODES+1 ints) 400004 -> pad 400128   [zeroed]
// 400128  : gsum   (128 f) 512                               [zeroed]
// 400640  : gsum2  (128 f) 512  -> 401152                    [zeroed]
// 401152  : cursor (N_NODES ints) 400000 -> pad 801280       [written by scan3]
// 801280  : bsum   (S1_BLOCKS ints) -> pad 801792            [written by scan1]
// 801792  : pairs  (N_EDGES float2) 12.8 MB
#define WS_ROWSTART 0
#define WS_GSUM     400128
#define WS_GSUM2    400640
#define WS_CURSOR   401152
#define WS_BSUM     801280
#define WS_PAIRS    801792
#define WS_ZERO_BYTES 401152

// ---------------- 1) histogram of dst ----------------
__global__ __launch_bounds__(256) void hist_kernel(
    const int* __restrict__ ei, int* __restrict__ rowstart)
{
    int e = blockIdx.x * 256 + threadIdx.x;
    if (e < N_EDGES) atomicAdd(&rowstart[1 + ei[N_EDGES + e]], 1);
}

// ---------------- 2a) per-block reduce of counts ----------------
__global__ __launch_bounds__(256) void scan1_kernel(
    const int* __restrict__ rowstart, int* __restrict__ bsum)
{
    __shared__ int red[256];
    const int t = threadIdx.x;
    const int base = blockIdx.x * S1_EPB + t * 4;
    int s = 0;
    #pragma unroll
    for (int k = 0; k < 4; ++k) {
        int idx = base + k;
        if (idx < SCAN_ELEMS) s += rowstart[idx];
    }
    red[t] = s;
    __syncthreads();
    for (int off = 128; off > 0; off >>= 1) {
        if (t < off) red[t] += red[t + off];
        __syncthreads();
    }
    if (t == 0) bsum[blockIdx.x] = red[0];
}

// ---------------- 2b) exclusive scan of block sums (tiny) ----------------
__global__ __launch_bounds__(128) void scan2_kernel(int* __restrict__ bsum)
{
    __shared__ int buf[128];
    const int t = threadIdx.x;
    buf[t] = (t < S1_BLOCKS) ? bsum[t] : 0;
    __syncthreads();
    for (int off = 1; off < 128; off <<= 1) {
        int v = (t >= off) ? buf[t - off] : 0;
        __syncthreads();
        buf[t] += v;
        __syncthreads();
    }
    if (t < S1_BLOCKS) bsum[t] = (t > 0) ? buf[t - 1] : 0;   // exclusive
}

// ---------------- 2c) block-local inclusive scan + offset ----------------
__global__ __launch_bounds__(256) void scan3_kernel(
    int* __restrict__ rowstart, int* __restrict__ cursor,
    const int* __restrict__ bsum)
{
    __shared__ int tsum[256];
    const int t = threadIdx.x;
    const int base = blockIdx.x * S1_EPB + t * 4;
    int c0 = 0, c1 = 0, c2 = 0, c3 = 0;
    if (base + 3 < SCAN_ELEMS) {
        c0 = rowstart[base]; c1 = rowstart[base + 1];
        c2 = rowstart[base + 2]; c3 = rowstart[base + 3];
    } else {
        if (base + 0 < SCAN_ELEMS) c0 = rowstart[base + 0];
        if (base + 1 < SCAN_ELEMS) c1 = rowstart[base + 1];
        if (base + 2 < SCAN_ELEMS) c2 = rowstart[base + 2];
        if (base + 3 < SCAN_ELEMS) c3 = rowstart[base + 3];
    }
    const int i0 = c0, i1 = i0 + c1, i2 = i1 + c2, i3 = i2 + c3;
    tsum[t] = i3;
    __syncthreads();
    for (int off = 1; off < 256; off <<= 1) {
        int v = (t >= off) ? tsum[t - off] : 0;
        __syncthreads();
        tsum[t] += v;
        __syncthreads();
    }
    const int boff = bsum[blockIdx.x] + tsum[t] - i3;   // exclusive thread offset
    const int r0 = boff + i0, r1 = boff + i1, r2 = boff + i2, r3 = boff + i3;
    if (base + 0 < SCAN_ELEMS) rowstart[base + 0] = r0;
    if (base + 1 < SCAN_ELEMS) rowstart[base + 1] = r1;
    if (base + 2 < SCAN_ELEMS) rowstart[base + 2] = r2;
    if (base + 3 < SCAN_ELEMS) rowstart[base + 3] = r3;
    if (base + 0 < N_NODES) cursor[base + 0] = r0;
    if (base + 1 < N_NODES) cursor[base + 1] = r1;
    if (base + 2 < N_NODES) cursor[base + 2] = r2;
    if (base + 3 < N_NODES) cursor[base + 3] = r3;
}

// ---------------- 3) fill (src, w) pairs per dst bucket ----------------
__global__ __launch_bounds__(256) void fill_kernel(
    const int* __restrict__ ei, const float* __restrict__ ew,
    int* __restrict__ cursor, float2* __restrict__ pairs)
{
    int e = blockIdx.x * 256 + threadIdx.x;
    if (e >= N_EDGES) return;
    int src = ei[e];
    int dst = ei[N_EDGES + e];
    int pos = atomicAdd(&cursor[dst], 1);
    pairs[pos] = make_float2(__int_as_float(src), ew[e]);
}

// ---------------- 4) fused gather + (agg+x)@W1+b1 + BN partial stats ----------------
#define B1_NPW 5   // nodes per wave -> grid = 100000/(4*5) = 5000 blocks
__global__ __launch_bounds__(256) void mlp1_kernel(
    const float* __restrict__ x,
    const int* __restrict__ rowstart,
    const float2* __restrict__ pairs,
    const float* __restrict__ W1,   // [64,128] row-major
    const float* __restrict__ b1,
    float* __restrict__ h,          // [N,128]
    float* __restrict__ gsum, float* __restrict__ gsum2)
{
    __shared__ float w1s[IN_DIM][EMB];     // 32 KB
    __shared__ float rowbuf[4][IN_DIM];    // per-wave row
    __shared__ float red[4][2][EMB];       // per-wave col partials

    const int tid  = threadIdx.x;
    const int lane = tid & 63;
    const int wid  = tid >> 6;
    const int lane64 = lane + 64;

    for (int i = tid; i < IN_DIM * EMB; i += 256)
        w1s[i >> 7][i & 127] = W1[i];
    const float bl0 = b1[lane], bl1 = b1[lane64];
    __syncthreads();   // w1s ready

    float s0 = 0.f, s20 = 0.f, s1 = 0.f, s21 = 0.f;
    const int node0 = (blockIdx.x * 4 + wid) * B1_NPW;

    for (int r = 0; r < B1_NPW; ++r) {
        const int n  = node0 + r;
        const int jb = rowstart[n];
        const int je = rowstart[n + 1];

        float accA = x[(size_t)n * IN_DIM + lane];   // self term, (1+eps)=1
        float accB = 0.f;
        for (int j0 = jb; j0 < je; j0 += 64) {
            const int cnt = min(64, je - j0);
            float2 p = (lane < cnt) ? pairs[j0 + lane] : make_float2(0.f, 0.f);
            int   psrc = __float_as_int(p.x);
            float pw   = p.y;
            const int nch = (cnt + 15) >> 4;
            for (int c = 0; c < nch; ++c) {
                const int base = c * 16;
                #pragma unroll
                for (int t = 0; t < 16; t += 2) {
                    int   sA = __shfl(psrc, base + t);
                    float wA = __shfl(pw,   base + t);
                    int   sB = __shfl(psrc, base + t + 1);
                    float wB = __shfl(pw,   base + t + 1);
                    accA += wA * x[(size_t)sA * IN_DIM + lane];
                    accB += wB * x[(size_t)sB * IN_DIM + lane];
                }
            }
        }
        rowbuf[wid][lane] = accA + accB;

        float a0 = bl0, a1 = bl1;
        const float4* rb4 = (const float4*)rowbuf[wid];
        #pragma unroll
        for (int kg = 0; kg < 16; ++kg) {
            float4 rv = rb4[kg];
            int k = kg * 4;
            a0 += rv.x * w1s[k][lane]   + rv.y * w1s[k+1][lane]
                + rv.z * w1s[k+2][lane] + rv.w * w1s[k+3][lane];
            a1 += rv.x * w1s[k][lane64]   + rv.y * w1s[k+1][lane64]
                + rv.z * w1s[k+2][lane64] + rv.w * w1s[k+3][lane64];
        }
        h[(size_t)n * EMB + lane]   = a0;
        h[(size_t)n * EMB + lane64] = a1;
        s0 += a0; s20 += a0 * a0;
        s1 += a1; s21 += a1 * a1;
    }

    red[wid][0][lane] = s0;  red[wid][0][lane64] = s1;
    red[wid][1][lane] = s20; red[wid][1][lane64] = s21;
    __syncthreads();
    if (tid < EMB) {
        float t0 = red[0][0][tid] + red[1][0][tid] + red[2][0][tid] + red[3][0][tid];
        float t1 = red[0][1][tid] + red[1][1][tid] + red[2][1][tid] + red[3][1][tid];
        atomicAdd(&gsum[tid],  t0);
        atomicAdd(&gsum2[tid], t1);
    }
}

// ---------------- 5) out = relu(BN(h)) @ W2 + b2 (in-place on h) ----------------
#define E_ROWS 40   // rows per block
__global__ __launch_bounds__(256) void mlp2_kernel(
    float* __restrict__ hio,
    const float* __restrict__ gsum, const float* __restrict__ gsum2,
    const float* __restrict__ gamma, const float* __restrict__ beta,
    const float* __restrict__ W2,   // [128,128] row-major
    const float* __restrict__ b2)
{
    __shared__ float w2t[EMB][132];   // transposed + padded
    __shared__ float nbuf[8][EMB];

    const int tid = threadIdx.x;
    const int col = tid & 127;
    const int rh  = tid >> 7;

    for (int i = tid; i < EMB * EMB; i += 256) {
        int k = i >> 7, j = i & 127;
        w2t[j][k] = W2[i];
    }
    const float invN = 1.0f / (float)N_NODES;
    float mean = gsum[col] * invN;
    float var  = gsum2[col] * invN - mean * mean;
    float inv  = rsqrtf(var + BN_EPS);
    float a    = gamma[col] * inv;
    float bb   = beta[col] - mean * a;
    float bj   = b2[col];

    const int row0 = blockIdx.x * E_ROWS;
    for (int it = 0; it < E_ROWS / 8; ++it) {
        const int rbase = row0 + it * 8;
        __syncthreads();
        #pragma unroll
        for (int rr = 0; rr < 4; ++rr) {
            int lr = rh * 4 + rr;
            float hv = hio[(size_t)(rbase + lr) * EMB + col];
            nbuf[lr][col] = fmaxf(hv * a + bb, 0.f);
        }
        __syncthreads();
        float4 acc = make_float4(bj, bj, bj, bj);
        const float4* wt4 = (const float4*)&w2t[col][0];
        const float4* n0 = (const float4*)&nbuf[rh * 4 + 0][0];
        const float4* n1 = (const float4*)&nbuf[rh * 4 + 1][0];
        const float4* n2 = (const float4*)&nbuf[rh * 4 + 2][0];
        const float4* n3 = (const float4*)&nbuf[rh * 4 + 3][0];
        #pragma unroll 8
        for (int kg = 0; kg < 32; ++kg) {
            float4 wv = wt4[kg];
            float4 v0 = n0[kg], v1 = n1[kg], v2 = n2[kg], v3 = n3[kg];
            acc.x += wv.x*v0.x + wv.y*v0.y + wv.z*v0.z + wv.w*v0.w;
            acc.y += wv.x*v1.x + wv.y*v1.y + wv.z*v1.z + wv.w*v1.w;
            acc.z += wv.x*v2.x + wv.y*v2.y + wv.z*v2.z + wv.w*v2.w;
            acc.w += wv.x*v3.x + wv.y*v3.y + wv.z*v3.z + wv.w*v3.w;
        }
        hio[(size_t)(rbase + rh*4 + 0) * EMB + col] = acc.x;
        hio[(size_t)(rbase + rh*4 + 1) * EMB + col] = acc.y;
        hio[(size_t)(rbase + rh*4 + 2) * EMB + col] = acc.z;
        hio[(size_t)(rbase + rh*4 + 3) * EMB + col] = acc.w;
    }
}

extern "C" void kernel_launch(void* const* d_in, const int* in_sizes, int n_in,
                              void* d_out, int out_size, void* d_ws, size_t ws_size,
                              hipStream_t stream)
{
    const float* x     = (const float*)d_in[0];
    const int*   ei    = (const int*)d_in[1];   // int32 [2,E]
    const float* ew    = (const float*)d_in[3];
    const float* W1    = (const float*)d_in[4];
    const float* b1    = (const float*)d_in[5];
    const float* gamma = (const float*)d_in[6];
    const float* beta  = (const float*)d_in[7];
    const float* W2    = (const float*)d_in[8];
    const float* b2    = (const float*)d_in[9];

    char* ws = (char*)d_ws;
    int*    rowstart = (int*)(ws + WS_ROWSTART);
    int*    cursor   = (int*)(ws + WS_CURSOR);
    float*  gsum     = (float*)(ws + WS_GSUM);
    float*  gsum2    = (float*)(ws + WS_GSUM2);
    int*    bsum     = (int*)(ws + WS_BSUM);
    float2* pairs    = (float2*)(ws + WS_PAIRS);
    float*  h        = (float*)d_out;

    hipMemsetAsync(d_ws, 0, WS_ZERO_BYTES, stream);

    hist_kernel<<<(N_EDGES + 255) / 256, 256, 0, stream>>>(ei, rowstart);
    scan1_kernel<<<S1_BLOCKS, 256, 0, stream>>>(rowstart, bsum);
    scan2_kernel<<<1, 128, 0, stream>>>(bsum);
    scan3_kernel<<<S1_BLOCKS, 256, 0, stream>>>(rowstart, cursor, bsum);
    fill_kernel<<<(N_EDGES + 255) / 256, 256, 0, stream>>>(ei, ew, cursor, pairs);
    mlp1_kernel<<<N_NODES / (4 * B1_NPW), 256, 0, stream>>>(x, rowstart, pairs, W1, b1, h, gsum, gsum2);
    mlp2_kernel<<<N_NODES / E_ROWS, 256, 0, stream>>>(h, gsum, gsum2, gamma, beta, W2, b2);
}